// Round 9
// baseline (204.298 us; speedup 1.0000x reference)
//
#include <hip/hip_runtime.h>
#include <hip/hip_bf16.h>

#define D_IN   2048
#define D_ST   16
#define DT_RK  64
#define BB     2
#define LL     2048
#define NCHUNK 64
#define LC     (LL / NCHUNK)   // 32
#define LOG2E  1.4426950408889634f
#define LN2    0.6931471805599453f

static __device__ __forceinline__ unsigned short f2bf(float v) {
    __hip_bfloat16 h = __float2bfloat16(v);
    return *(unsigned short*)&h;
}

// ---------------------------------------------------------------------------
// Kernel 1: x_dbl[bl][k] = sum_d u[bl][d] * W_x[k][d]   (M=4096, N=96, K=2048)
// 128x96 tile, KSPLIT=16, k-major LDS, 8x6 micro-tile. (unchanged from R8)
// ---------------------------------------------------------------------------
#define X1_KSPLIT 16
#define X1_LDA 132
#define X1_LDB 100

__global__ __launch_bounds__(256, 4) void gemm_xdbl(const float* __restrict__ u,
                                                    const float* __restrict__ Wx,
                                                    float* __restrict__ part) {
    __shared__ float As[64][X1_LDA];   // [k][row 0..127]
    __shared__ float Bs[64][X1_LDB];   // [k][col 0..95]
    const int mt = blockIdx.x >> 4;
    const int ks = blockIdx.x & 15;
    const int row0 = mt * 128;
    const int kb0  = ks * 128;
    const int tid = threadIdx.x;
    const int ty = tid >> 4;
    const int tx = tid & 15;

    float acc[8][6];
#pragma unroll
    for (int i = 0; i < 8; i++)
#pragma unroll
        for (int j = 0; j < 6; j++) acc[i][j] = 0.f;

    for (int kc = 0; kc < 128; kc += 64) {
        const int kb = kb0 + kc;
#pragma unroll
        for (int i = 0; i < 8; i++) {
            int f = tid + i * 256;
            int r = f >> 4, kg = f & 15;
            float4 a = *(const float4*)&u[(size_t)(row0 + r) * D_IN + kb + kg * 4];
            As[kg * 4 + 0][r] = a.x; As[kg * 4 + 1][r] = a.y;
            As[kg * 4 + 2][r] = a.z; As[kg * 4 + 3][r] = a.w;
        }
#pragma unroll
        for (int i = 0; i < 6; i++) {
            int f = tid + i * 256;
            int c = f >> 4, kg = f & 15;
            float4 b = *(const float4*)&Wx[(size_t)c * D_IN + kb + kg * 4];
            Bs[kg * 4 + 0][c] = b.x; Bs[kg * 4 + 1][c] = b.y;
            Bs[kg * 4 + 2][c] = b.z; Bs[kg * 4 + 3][c] = b.w;
        }
        __syncthreads();
#pragma unroll 2
        for (int k = 0; k < 64; k++) {
            float4 a0 = *(const float4*)&As[k][ty * 8];
            float4 a1 = *(const float4*)&As[k][ty * 8 + 4];
            float2 b0 = *(const float2*)&Bs[k][tx * 6];
            float2 b1 = *(const float2*)&Bs[k][tx * 6 + 2];
            float2 b2 = *(const float2*)&Bs[k][tx * 6 + 4];
            const float av[8] = {a0.x,a0.y,a0.z,a0.w, a1.x,a1.y,a1.z,a1.w};
            const float bv[6] = {b0.x,b0.y, b1.x,b1.y, b2.x,b2.y};
#pragma unroll
            for (int i = 0; i < 8; i++)
#pragma unroll
                for (int j = 0; j < 6; j++)
                    acc[i][j] = fmaf(av[i], bv[j], acc[i][j]);
        }
        __syncthreads();
    }
    float* pp = part + (size_t)ks * (BB * LL * 96);
#pragma unroll
    for (int i = 0; i < 8; i++) {
        float* op = &pp[(size_t)(row0 + ty * 8 + i) * 96 + tx * 6];
        *(float2*)&op[0] = make_float2(acc[i][0], acc[i][1]);
        *(float2*)&op[2] = make_float2(acc[i][2], acc[i][3]);
        *(float2*)&op[4] = make_float2(acc[i][4], acc[i][5]);
    }
}

// Reduce the 16 split-K partials into xdbl.
__global__ __launch_bounds__(256) void reduce_xdbl(const float* __restrict__ part,
                                                   float* __restrict__ xdbl) {
    const size_t i4 = ((size_t)blockIdx.x * 256 + threadIdx.x) * 4;
    const size_t stride = (size_t)BB * LL * 96;
    float4 s = *(const float4*)&part[i4];
#pragma unroll
    for (int k = 1; k < X1_KSPLIT; k++) {
        float4 v = *(const float4*)&part[k * stride + i4];
        s.x += v.x; s.y += v.y; s.z += v.z; s.w += v.w;
    }
    *(float4*)&xdbl[i4] = s;
}

// ---------------------------------------------------------------------------
// Kernel 2: dt = softplus(xdbl[:, :64] @ Wdt^T + b), output BF16 (unchanged).
// ---------------------------------------------------------------------------
#define G2_LDA 132

__global__ __launch_bounds__(256, 4) void gemm_dt(const float* __restrict__ xdbl,
                                                  const float* __restrict__ Wdt,
                                                  const float* __restrict__ bdt,
                                                  __hip_bfloat16* __restrict__ dt) {
    __shared__ float As[DT_RK][G2_LDA];
    __shared__ float Bs[DT_RK][G2_LDA];
    const int rt = blockIdx.x >> 4;
    const int ct = blockIdx.x & 15;
    const int row0 = rt * 128, col0 = ct * 128;
    const int tid = threadIdx.x;

#pragma unroll
    for (int i = 0; i < 8; i++) {
        int f = tid + i * 256;
        int r  = f >> 4;
        int kg = f & 15;
        float4 a = *(const float4*)&xdbl[(size_t)(row0 + r) * 96 + kg * 4];
        float4 b = *(const float4*)&Wdt[(size_t)(col0 + r) * DT_RK + kg * 4];
        As[kg * 4 + 0][r] = a.x; As[kg * 4 + 1][r] = a.y;
        As[kg * 4 + 2][r] = a.z; As[kg * 4 + 3][r] = a.w;
        Bs[kg * 4 + 0][r] = b.x; Bs[kg * 4 + 1][r] = b.y;
        Bs[kg * 4 + 2][r] = b.z; Bs[kg * 4 + 3][r] = b.w;
    }
    __syncthreads();

    const int ty = tid >> 4;
    const int tx = tid & 15;
    float acc[8][8];
#pragma unroll
    for (int i = 0; i < 8; i++)
#pragma unroll
        for (int j = 0; j < 8; j++) acc[i][j] = 0.f;

#pragma unroll 2
    for (int k = 0; k < DT_RK; k++) {
        float4 a0 = *(const float4*)&As[k][ty * 4];
        float4 a1 = *(const float4*)&As[k][ty * 4 + 64];
        float4 b0 = *(const float4*)&Bs[k][tx * 4];
        float4 b1 = *(const float4*)&Bs[k][tx * 4 + 64];
        const float av[8] = {a0.x,a0.y,a0.z,a0.w, a1.x,a1.y,a1.z,a1.w};
        const float bv[8] = {b0.x,b0.y,b0.z,b0.w, b1.x,b1.y,b1.z,b1.w};
#pragma unroll
        for (int i = 0; i < 8; i++)
#pragma unroll
            for (int j = 0; j < 8; j++)
                acc[i][j] = fmaf(av[i], bv[j], acc[i][j]);
    }

    float4 bj0 = *(const float4*)&bdt[col0 + tx * 4];
    float4 bj1 = *(const float4*)&bdt[col0 + 64 + tx * 4];
    const float bj[8] = {bj0.x,bj0.y,bj0.z,bj0.w, bj1.x,bj1.y,bj1.z,bj1.w};
#pragma unroll
    for (int i = 0; i < 8; i++) {
        const int row = row0 + ((i < 4) ? (ty * 4 + i) : (64 + ty * 4 + i - 4));
        float o[8];
#pragma unroll
        for (int j = 0; j < 8; j++) {
            float xv = acc[i][j] + bj[j];
            float t = __builtin_amdgcn_exp2f(-fabsf(xv) * LOG2E);
            o[j] = fmaxf(xv, 0.f) + LN2 * __log2f(1.f + t);
        }
        unsigned short* op = (unsigned short*)dt + (size_t)row * D_IN + col0 + tx * 4;
        ushort4 p0, p1;
        p0.x = f2bf(o[0]); p0.y = f2bf(o[1]); p0.z = f2bf(o[2]); p0.w = f2bf(o[3]);
        p1.x = f2bf(o[4]); p1.y = f2bf(o[5]); p1.z = f2bf(o[6]); p1.w = f2bf(o[7]);
        *(ushort4*)&op[0]  = p0;
        *(ushort4*)&op[64] = p1;
    }
}

// ---------------------------------------------------------------------------
// Scan pass 1: register-preloaded u/dt (48 independent loads up front),
// B staged once into LDS. Fully unrolled pure-VALU t-loop.
// ---------------------------------------------------------------------------
__global__ __launch_bounds__(256, 3) void scan_pass1(const float* __restrict__ u,
                                                     const __hip_bfloat16* __restrict__ dt,
                                                     const float* __restrict__ xdbl,
                                                     const float* __restrict__ Alog,
                                                     float* __restrict__ Ssum,
                                                     float* __restrict__ q) {
    __shared__ float bc[LC][32];
    const int blk = blockIdx.x;
    const int b  = blk >> 9;
    const int c  = (blk >> 3) & 63;
    const int db = blk & 7;
    const int tid = threadIdx.x;
    const int d = db * 256 + tid;
    const int t0 = c * LC;

    {   // stage B/C rows once: 1024 floats, 1 f4/thread
        int t = tid >> 3, j4 = (tid & 7) * 4;
        *(float4*)&bc[t][j4] =
            *(const float4*)&xdbl[(size_t)(b * LL + t0 + t) * 96 + 64 + j4];
    }

    // preload the whole chunk: independent strided loads, one wait
    const float* up = &u[(size_t)(b * LL + t0) * D_IN + d];
    const __hip_bfloat16* dtp = &dt[(size_t)(b * LL + t0) * D_IN + d];
    float ur[LC], dtr[LC];
#pragma unroll
    for (int t = 0; t < LC; t++) ur[t] = up[(size_t)t * D_IN];
#pragma unroll
    for (int t = 0; t < LC; t++) dtr[t] = __bfloat162float(dtp[(size_t)t * D_IN]);

    float A2[16];
#pragma unroll
    for (int n4 = 0; n4 < 4; n4++) {
        float4 a = *(const float4*)&Alog[(size_t)d * 16 + n4 * 4];
        A2[n4 * 4 + 0] = -expf(a.x) * LOG2E;
        A2[n4 * 4 + 1] = -expf(a.y) * LOG2E;
        A2[n4 * 4 + 2] = -expf(a.z) * LOG2E;
        A2[n4 * 4 + 3] = -expf(a.w) * LOG2E;
    }
    __syncthreads();

    float h[16];
#pragma unroll
    for (int n = 0; n < 16; n++) h[n] = 0.f;
    float S = 0.f;

#pragma unroll
    for (int t = 0; t < LC; t++) {
        float dv = dtr[t], uv = ur[t];
        S += dv;
        float dtu = dv * uv;
        float4 b0 = *(const float4*)&bc[t][0];
        float4 b1 = *(const float4*)&bc[t][4];
        float4 b2 = *(const float4*)&bc[t][8];
        float4 b3 = *(const float4*)&bc[t][12];
        const float Bt[16] = {b0.x,b0.y,b0.z,b0.w, b1.x,b1.y,b1.z,b1.w,
                              b2.x,b2.y,b2.z,b2.w, b3.x,b3.y,b3.z,b3.w};
#pragma unroll
        for (int n = 0; n < 16; n++) {
            float a = __builtin_amdgcn_exp2f(dv * A2[n]);
            h[n] = fmaf(a, h[n], dtu * Bt[n]);
        }
    }
    Ssum[(size_t)(b * NCHUNK + c) * D_IN + d] = S;
#pragma unroll
    for (int n = 0; n < 16; n++)
        q[((size_t)((b * NCHUNK + c) * 16 + n)) * D_IN + d] = h[n];
}

// ---------------------------------------------------------------------------
// Combine v2: 4 segments of 16 chunks per (b,n,d). Phase 1: register-cached
// loads + local fold (F,P). 4-lane shuffle composition. Phase 2: write h_init
// in-place over q. Depth 64 -> 16, ILP=16, 4x the waves.
// ---------------------------------------------------------------------------
__global__ __launch_bounds__(256) void scan_combine(const float* __restrict__ Alog,
                                                    const float* __restrict__ Ssum,
                                                    float* __restrict__ q) {
    const int gid = blockIdx.x * 256 + threadIdx.x;  // B*16*2048*4 = 262144
    const int seg = gid & 3;
    const int d   = (gid >> 2) & 2047;
    const int n   = (gid >> 13) & 15;
    const int b   = gid >> 17;
    const float A2 = -expf(Alog[(size_t)d * 16 + n]) * LOG2E;
    const size_t qstride = (size_t)16 * D_IN;
    const int c0 = seg * 16;
    const size_t idx0 = ((size_t)((b * NCHUNK + c0) * 16 + n)) * D_IN + d;
    const float* sp = &Ssum[(size_t)(b * NCHUNK + c0) * D_IN + d];

    float qv[16], a[16];
#pragma unroll
    for (int i = 0; i < 16; i++) qv[i] = q[idx0 + (size_t)i * qstride];
#pragma unroll
    for (int i = 0; i < 16; i++) a[i] = __builtin_amdgcn_exp2f(A2 * sp[(size_t)i * D_IN]);

    float F = 0.f, P = 1.f;
#pragma unroll
    for (int i = 0; i < 16; i++) { F = fmaf(a[i], F, qv[i]); P *= a[i]; }

    // compose across the 4 lanes of this (b,n,d) group
    const int lane = threadIdx.x & 63;
    const int base = lane & ~3;
    float hin = 0.f;
#pragma unroll
    for (int s = 0; s < 3; s++) {
        float Fs = __shfl(F, base + s);
        float Ps = __shfl(P, base + s);
        hin = (seg > s) ? fmaf(Ps, hin, Fs) : hin;
    }

    float h = hin;
#pragma unroll
    for (int i = 0; i < 16; i++) {
        q[idx0 + (size_t)i * qstride] = h;    // h_init for chunk c0+i
        h = fmaf(a[i], h, qv[i]);
    }
}

// ---------------------------------------------------------------------------
// Scan pass 2: register-preloaded u/dt, LDS B/C, emit y (fp32).
// ---------------------------------------------------------------------------
__global__ __launch_bounds__(256, 3) void scan_pass2(const float* __restrict__ u,
                                                     const __hip_bfloat16* __restrict__ dt,
                                                     const float* __restrict__ xdbl,
                                                     const float* __restrict__ Alog,
                                                     const float* __restrict__ Dv,
                                                     const float* __restrict__ hinit,
                                                     float* __restrict__ out) {
    __shared__ float bc[LC][32];
    const int blk = blockIdx.x;
    const int b  = blk >> 9;
    const int c  = (blk >> 3) & 63;
    const int db = blk & 7;
    const int tid = threadIdx.x;
    const int d = db * 256 + tid;
    const int t0 = c * LC;

    {
        int t = tid >> 3, j4 = (tid & 7) * 4;
        *(float4*)&bc[t][j4] =
            *(const float4*)&xdbl[(size_t)(b * LL + t0 + t) * 96 + 64 + j4];
    }

    const float* up = &u[(size_t)(b * LL + t0) * D_IN + d];
    const __hip_bfloat16* dtp = &dt[(size_t)(b * LL + t0) * D_IN + d];
    float ur[LC], dtr[LC];
#pragma unroll
    for (int t = 0; t < LC; t++) ur[t] = up[(size_t)t * D_IN];
#pragma unroll
    for (int t = 0; t < LC; t++) dtr[t] = __bfloat162float(dtp[(size_t)t * D_IN]);

    float A2[16];
#pragma unroll
    for (int n4 = 0; n4 < 4; n4++) {
        float4 a = *(const float4*)&Alog[(size_t)d * 16 + n4 * 4];
        A2[n4 * 4 + 0] = -expf(a.x) * LOG2E;
        A2[n4 * 4 + 1] = -expf(a.y) * LOG2E;
        A2[n4 * 4 + 2] = -expf(a.z) * LOG2E;
        A2[n4 * 4 + 3] = -expf(a.w) * LOG2E;
    }
    const float Dd = Dv[d];
    float h[16];
#pragma unroll
    for (int n = 0; n < 16; n++)
        h[n] = hinit[((size_t)((b * NCHUNK + c) * 16 + n)) * D_IN + d];
    __syncthreads();

    float* op = &out[(size_t)(b * LL + t0) * D_IN + d];
#pragma unroll
    for (int t = 0; t < LC; t++) {
        float dv = dtr[t], uv = ur[t];
        float dtu = dv * uv;
        float4 b0 = *(const float4*)&bc[t][0];
        float4 b1 = *(const float4*)&bc[t][4];
        float4 b2 = *(const float4*)&bc[t][8];
        float4 b3 = *(const float4*)&bc[t][12];
        float4 c0v = *(const float4*)&bc[t][16];
        float4 c1v = *(const float4*)&bc[t][20];
        float4 c2v = *(const float4*)&bc[t][24];
        float4 c3v = *(const float4*)&bc[t][28];
        const float Bt[16] = {b0.x,b0.y,b0.z,b0.w, b1.x,b1.y,b1.z,b1.w,
                              b2.x,b2.y,b2.z,b2.w, b3.x,b3.y,b3.z,b3.w};
        const float Ct[16] = {c0v.x,c0v.y,c0v.z,c0v.w, c1v.x,c1v.y,c1v.z,c1v.w,
                              c2v.x,c2v.y,c2v.z,c2v.w, c3v.x,c3v.y,c3v.z,c3v.w};
        float y = 0.f;
#pragma unroll
        for (int n = 0; n < 16; n++) {
            float a = __builtin_amdgcn_exp2f(dv * A2[n]);
            h[n] = fmaf(a, h[n], dtu * Bt[n]);
            y = fmaf(h[n], Ct[n], y);
        }
        op[(size_t)t * D_IN] = fmaf(uv, Dd, y);
    }
}

// ---------------------------------------------------------------------------
extern "C" void kernel_launch(void* const* d_in, const int* in_sizes, int n_in,
                              void* d_out, int out_size, void* d_ws, size_t ws_size,
                              hipStream_t stream) {
    const float* u    = (const float*)d_in[0];
    const float* Alog = (const float*)d_in[1];
    const float* Dv   = (const float*)d_in[2];
    const float* Wx   = (const float*)d_in[3];
    const float* Wdt  = (const float*)d_in[4];
    const float* bdt  = (const float*)d_in[5];
    float* out = (float*)d_out;

    float* ws   = (float*)d_ws;
    float* xdbl = ws;                                   // 393216 f
    __hip_bfloat16* dtb = (__hip_bfloat16*)(ws + 393216);   // 4194304 f worth
    float* Ssum = ws + 393216 + 4194304;
    float* q    = Ssum + (size_t)BB * NCHUNK * D_IN;
    float* part = ws + 393216;   // 16*393216 f, aliases dtb+Ssum+q (dead after reduce)

    gemm_xdbl <<<32 * X1_KSPLIT, 256, 0, stream>>>(u, Wx, part);
    reduce_xdbl<<<384,           256, 0, stream>>>(part, xdbl);
    gemm_dt   <<<32 * 16,        256, 0, stream>>>(xdbl, Wdt, bdt, dtb);
    scan_pass1<<<BB * NCHUNK * 8, 256, 0, stream>>>(u, dtb, xdbl, Alog, Ssum, q);
    scan_combine<<<BB * 16 * D_IN * 4 / 256, 256, 0, stream>>>(Alog, Ssum, q);
    scan_pass2<<<BB * NCHUNK * 8, 256, 0, stream>>>(u, dtb, xdbl, Alog, Dv, q, out);
}